// Round 9
// baseline (1190.490 us; speedup 1.0000x reference)
//
#include <hip/hip_runtime.h>
#include <hip/hip_bf16.h>

#define D_IN  32
#define D_EF  16
#define D_H   64
#define D_MSG 32
#define D_UP  32

// NOTE: __builtin_amdgcn_cvt_pkrtz / fdot2 use the __fp16-based vector type;
// _Float16-based ext vectors are treated as incompatible by clang.
typedef __fp16 v2h __attribute__((ext_vector_type(2)));

// bf16 helpers: pack two fp32 -> uint32 (RNE), unpack low/high half
__device__ __forceinline__ unsigned bf16pair(float a, float b) {
    unsigned ua = __float_as_uint(a);
    ua = (ua + 0x7fffu + ((ua >> 16) & 1u)) >> 16;
    unsigned ub = __float_as_uint(b);
    ub = (ub + 0x7fffu + ((ub >> 16) & 1u)) >> 16;
    return ua | (ub << 16);
}
__device__ __forceinline__ float bf_lo(unsigned u) { return __uint_as_float(u << 16); }
__device__ __forceinline__ float bf_hi(unsigned u) { return __uint_as_float(u & 0xffff0000u); }
__device__ __forceinline__ v2h u2h(unsigned u) {
    union { unsigned u; v2h h; } c; c.u = u; return c.h;
}

// ---------------------------------------------------------------------------
// Fused front-end (independent stages dispatched by block range):
//   blocks [0, NBn)                  : node_pre (P1 fp32, P2 bf16)
//   blocks [NBn, NBn+NBe)            : hist + rank (atomicAdd returns rank)
//   block  NBn+NBe                   : W1E pair-packing for fdot2
//   blocks (NBn+NBe, NBn+NBe+NBc]    : ef -> fp16 prepack (only if efh fits;
//                                      streamed once, overlaps hist latency)
// ---------------------------------------------------------------------------
__global__ __launch_bounds__(256) void prep_kernel(
    const float* __restrict__ x,
    const float* __restrict__ W1m,
    const float* __restrict__ b1m,
    const float* __restrict__ ef,
    const int*   __restrict__ ei,
    float* __restrict__ P1,
    unsigned short* __restrict__ P2b,
    int* __restrict__ deg,
    int* __restrict__ rank,
    v2h* __restrict__ W1Ep,
    v2h* __restrict__ efh,
    int n_nodes, int n_edges, int NBn, int NBe)
{
    int b = blockIdx.x;

    if (b < NBn) {
        // ---------------- node_pre ----------------
        int i = b * 256 + threadIdx.x;
        if (i >= n_nodes) return;

        float xi[D_IN];
        const float4* xp = (const float4*)(x + (size_t)i * D_IN);
#pragma unroll
        for (int k4 = 0; k4 < D_IN / 4; ++k4) {
            float4 v = xp[k4];
            xi[4 * k4 + 0] = v.x; xi[4 * k4 + 1] = v.y;
            xi[4 * k4 + 2] = v.z; xi[4 * k4 + 3] = v.w;
        }
        {
            float acc[D_H];
#pragma unroll
            for (int j = 0; j < D_H; ++j) acc[j] = b1m[j];
            for (int k = 0; k < D_IN; ++k) {
                float xv = xi[k];
                const float* wr = W1m + (size_t)k * D_H;
#pragma unroll
                for (int j = 0; j < D_H; ++j) acc[j] += xv * wr[j];
            }
            float4* o = (float4*)(P1 + (size_t)i * D_H);
#pragma unroll
            for (int j4 = 0; j4 < D_H / 4; ++j4)
                o[j4] = make_float4(acc[4 * j4], acc[4 * j4 + 1],
                                    acc[4 * j4 + 2], acc[4 * j4 + 3]);
        }
        {
            float acc[D_H];
#pragma unroll
            for (int j = 0; j < D_H; ++j) acc[j] = 0.0f;
            for (int k = 0; k < D_IN; ++k) {
                float xv = xi[k];
                const float* wr = W1m + (size_t)(k + D_IN) * D_H;
#pragma unroll
                for (int j = 0; j < D_H; ++j) acc[j] += xv * wr[j];
            }
            uint4* o = (uint4*)(P2b + (size_t)i * D_H);
#pragma unroll
            for (int j8 = 0; j8 < D_H / 8; ++j8) {
                uint4 q;
                q.x = bf16pair(acc[8 * j8 + 0], acc[8 * j8 + 1]);
                q.y = bf16pair(acc[8 * j8 + 2], acc[8 * j8 + 3]);
                q.z = bf16pair(acc[8 * j8 + 4], acc[8 * j8 + 5]);
                q.w = bf16pair(acc[8 * j8 + 6], acc[8 * j8 + 7]);
                o[j8] = q;
            }
        }
    } else if (b < NBn + NBe) {
        // ---------------- hist + rank ----------------
        int e = (b - NBn) * 256 + threadIdx.x;
        if (e < n_edges)
            rank[e] = atomicAdd(&deg[ei[n_edges + e]], 1);
    } else if (b == NBn + NBe) {
        // ---------------- pack W1E for fdot2: [kp][c] ----------------
        int t = threadIdx.x;
        const float* W1E = W1m + (size_t)(2 * D_IN) * D_H;
        for (int idx = t; idx < 8 * D_H; idx += 256) {
            int kp = idx >> 6, c = idx & 63;
            W1Ep[idx] = __builtin_amdgcn_cvt_pkrtz(W1E[(2 * kp) * D_H + c],
                                                   W1E[(2 * kp + 1) * D_H + c]);
        }
    } else {
        // ---------------- ef -> fp16 prepack (64 rows/block) ----------------
        int cb  = b - (NBn + NBe + 1);
        int row = cb * 64 + (threadIdx.x >> 2);
        int q   = threadIdx.x & 3;
        if (row < n_edges) {
            const float4* fp = (const float4*)(ef + (size_t)row * D_EF + q * 4);
            float4 f = fp[0];
            v2h* o = efh + (size_t)row * 8 + q * 2;
            o[0] = __builtin_amdgcn_cvt_pkrtz(f.x, f.y);
            o[1] = __builtin_amdgcn_cvt_pkrtz(f.z, f.w);
        }
    }
}

// ---------------------------------------------------------------------------
// 2-phase scan: reduce -> final (each final block redundantly scans the
// <=256 block sums in LDS; no 1-block middle kernel bubble).
// ---------------------------------------------------------------------------
__global__ __launch_bounds__(256) void scan_reduce_kernel(
    const int* __restrict__ deg, int* __restrict__ bsum, int n_nodes)
{
    int idx = blockIdx.x * 256 + threadIdx.x;
    int v = (idx < n_nodes) ? deg[idx] : 0;
#pragma unroll
    for (int o = 1; o < 64; o <<= 1) v += __shfl_xor(v, o, 64);
    __shared__ int ws[4];
    int lane = threadIdx.x & 63, w = threadIdx.x >> 6;
    if (lane == 0) ws[w] = v;
    __syncthreads();
    if (threadIdx.x == 0) bsum[blockIdx.x] = ws[0] + ws[1] + ws[2] + ws[3];
}

__global__ __launch_bounds__(256) void scan_final_kernel(
    const int* __restrict__ deg, const int* __restrict__ bsum,
    int* __restrict__ offs, int n_nodes, int nb)
{
    __shared__ int sb[256];
    __shared__ int sdata[256];
    int t = threadIdx.x;

    sb[t] = (t < nb) ? bsum[t] : 0;
    __syncthreads();
    for (int off = 1; off < 256; off <<= 1) {
        int u = (t >= off) ? sb[t - off] : 0;
        __syncthreads();
        sb[t] += u;
        __syncthreads();
    }
    int base = (blockIdx.x > 0) ? sb[blockIdx.x - 1] : 0;

    int idx = blockIdx.x * 256 + t;
    sdata[t] = (idx < n_nodes) ? deg[idx] : 0;
    __syncthreads();
    for (int off = 1; off < 256; off <<= 1) {
        int u = (t >= off) ? sdata[t - off] : 0;
        __syncthreads();
        sdata[t] += u;
        __syncthreads();
    }
    if (idx < n_nodes) offs[idx] = base + ((t > 0) ? sdata[t - 1] : 0);
}

// ---------------------------------------------------------------------------
// Atomic-free scatter: pos = offs[dst] + rank[e] (unique by construction).
// REGULAR stores (round-3 lesson: L2 write-merge makes this cheap; nt stores
// caused 13x write amplification).
// ---------------------------------------------------------------------------
__global__ __launch_bounds__(256) void scatter_kernel(
    const int* __restrict__ ei,
    const int* __restrict__ rank,
    const int* __restrict__ offs,
    int2* __restrict__ edges_sorted,
    int n_edges)
{
    int e = blockIdx.x * blockDim.x + threadIdx.x;
    if (e < n_edges) {
        int s = ei[e];
        int d = ei[n_edges + e];
        int pos = offs[d] + rank[e];
        edges_sorted[pos] = make_int2(e, s);
    }
}

// ---------------------------------------------------------------------------
// Gather-aggregate (round-2 proven main loop: 4 nodes/block, comp-quarter
// per wave, 16 edge-slots -> 16 edges in flight/wave) + efh fp16 ef rows +
// fused node-update epilogue (deletes hagg roundtrip + node_upd dispatch).
//
// __launch_bounds__(256, 6): round-8 lesson — the fused epilogue inflated
// VGPR to 100 and collapsed occupancy to 22% (296 us). Capping at ~85 VGPR
// keeps the ~48-VGPR main loop spill-free at >=6 waves/SIMD; any epilogue
// overflow spills to scratch ONCE per block (trivial).
// ---------------------------------------------------------------------------
template<int USE_EFH>
__global__ __launch_bounds__(256, 6) void gather_kernel(
    const float* __restrict__ ef,
    const v2h*  __restrict__ efh,
    const v2h*  __restrict__ W1Ep,
    const float* __restrict__ P1,
    const unsigned short* __restrict__ P2b,
    const int*  __restrict__ deg,
    const int*  __restrict__ offs,
    const int2* __restrict__ edges_sorted,
    const float* __restrict__ x,
    const float* __restrict__ b2m,
    const float* __restrict__ W2m,
    const float* __restrict__ W1u,
    const float* __restrict__ b1u,
    const float* __restrict__ W2u,
    const float* __restrict__ b2u,
    float* __restrict__ out,
    int n_nodes)
{
    __shared__ float hs[4][64];    // hsum exchange (4 nodes x 64 comps)
    __shared__ float in2[4][64];   // update-MLP input [x | aggm]
    __shared__ float rh[4][64];    // relu(h) of update layer 1

    const int tid  = threadIdx.x;
    const int lane = tid & 63;
    const int cq   = __builtin_amdgcn_readfirstlane(tid >> 6); // comp quarter
    const int g    = lane >> 4;        // node sub-index in block
    const int t    = lane & 15;        // edge slot
    const int n    = blockIdx.x * 4 + g;
    const bool valid = n < n_nodes;

    int start = 0, end = 0;
    if (valid) { start = offs[n]; end = start + deg[n]; }

    float p1q[16];
#pragma unroll
    for (int q = 0; q < 16; ++q) p1q[q] = 0.0f;
    if (valid) {
        const float4* pp = (const float4*)(P1 + (size_t)n * D_H + cq * 16);
#pragma unroll
        for (int q = 0; q < 4; ++q) {
            float4 v = pp[q];
            p1q[4 * q + 0] = v.x; p1q[4 * q + 1] = v.y;
            p1q[4 * q + 2] = v.z; p1q[4 * q + 3] = v.w;
        }
    }

    const v2h* wbase = W1Ep + 16 * cq;   // wave-uniform -> scalar loads

    float hacc[16];
#pragma unroll
    for (int c = 0; c < 16; ++c) hacc[c] = 0.0f;

    for (int i = start + t; i < end; i += 16) {
        int2 es = edges_sorted[i];

        v2h efr[8];
        if (USE_EFH) {
            const uint4* ep = (const uint4*)(efh + (size_t)(unsigned)es.x * 8);
            uint4 u0 = ep[0], u1 = ep[1];
            efr[0] = u2h(u0.x); efr[1] = u2h(u0.y);
            efr[2] = u2h(u0.z); efr[3] = u2h(u0.w);
            efr[4] = u2h(u1.x); efr[5] = u2h(u1.y);
            efr[6] = u2h(u1.z); efr[7] = u2h(u1.w);
        } else {
            const float4* efp = (const float4*)(ef + (size_t)(unsigned)es.x * D_EF);
            float4 f0 = efp[0], f1 = efp[1], f2 = efp[2], f3 = efp[3];
            efr[0] = __builtin_amdgcn_cvt_pkrtz(f0.x, f0.y);
            efr[1] = __builtin_amdgcn_cvt_pkrtz(f0.z, f0.w);
            efr[2] = __builtin_amdgcn_cvt_pkrtz(f1.x, f1.y);
            efr[3] = __builtin_amdgcn_cvt_pkrtz(f1.z, f1.w);
            efr[4] = __builtin_amdgcn_cvt_pkrtz(f2.x, f2.y);
            efr[5] = __builtin_amdgcn_cvt_pkrtz(f2.z, f2.w);
            efr[6] = __builtin_amdgcn_cvt_pkrtz(f3.x, f3.y);
            efr[7] = __builtin_amdgcn_cvt_pkrtz(f3.z, f3.w);
        }

        const uint4* p2u = (const uint4*)(P2b + (size_t)(unsigned)es.y * D_H + cq * 16);
        uint4 b0 = p2u[0], b1 = p2u[1];

#pragma unroll
        for (int jj = 0; jj < 2; ++jj) {
            uint4 bb = jj ? b1 : b0;
            float h[8];
            h[0] = p1q[8 * jj + 0] + bf_lo(bb.x);
            h[1] = p1q[8 * jj + 1] + bf_hi(bb.x);
            h[2] = p1q[8 * jj + 2] + bf_lo(bb.y);
            h[3] = p1q[8 * jj + 3] + bf_hi(bb.y);
            h[4] = p1q[8 * jj + 4] + bf_lo(bb.z);
            h[5] = p1q[8 * jj + 5] + bf_hi(bb.z);
            h[6] = p1q[8 * jj + 6] + bf_lo(bb.w);
            h[7] = p1q[8 * jj + 7] + bf_hi(bb.w);
#pragma unroll
            for (int kp = 0; kp < D_EF / 2; ++kp) {
                const v2h* wr = wbase + kp * D_H + 8 * jj;
#pragma unroll
                for (int c8 = 0; c8 < 8; ++c8)
                    h[c8] = __builtin_amdgcn_fdot2(efr[kp], wr[c8], h[c8], false);
            }
#pragma unroll
            for (int c8 = 0; c8 < 8; ++c8) {
                float r = h[c8] > 0.0f ? h[c8] : 0.0f;
                hacc[8 * jj + c8] += r;
            }
        }
    }

    // ---- 4-stage butterfly compaction across the node's 16 lanes ----
    float r1[8];
    {
        const bool up = (t & 8) != 0;
#pragma unroll
        for (int c = 0; c < 8; ++c) {
            float lo = hacc[c]     + __shfl_xor(hacc[c],     8, 16);
            float hi = hacc[c + 8] + __shfl_xor(hacc[c + 8], 8, 16);
            r1[c] = up ? hi : lo;
        }
    }
    float r2[4];
    {
        const bool up = (t & 4) != 0;
#pragma unroll
        for (int c = 0; c < 4; ++c) {
            float lo = r1[c]     + __shfl_xor(r1[c],     4, 16);
            float hi = r1[c + 4] + __shfl_xor(r1[c + 4], 4, 16);
            r2[c] = up ? hi : lo;
        }
    }
    float r3[2];
    {
        const bool up = (t & 2) != 0;
#pragma unroll
        for (int c = 0; c < 2; ++c) {
            float lo = r2[c]     + __shfl_xor(r2[c],     2, 16);
            float hi = r2[c + 2] + __shfl_xor(r2[c + 2], 2, 16);
            r3[c] = up ? hi : lo;
        }
    }
    float r4;
    {
        const bool up = (t & 1) != 0;
        float lo = r3[0] + __shfl_xor(r3[0], 1, 16);
        float hi = r3[1] + __shfl_xor(r3[1], 1, 16);
        r4 = up ? hi : lo;
    }

    // lane t holds comp (cq*16 + t) of node g
    hs[g][cq * 16 + t] = r4;
    __syncthreads();

    // ---------------- fused node update: wave cq handles node cq ------------
    const int nn = blockIdx.x * 4 + cq;
    if (nn < n_nodes) {
        // build in2 = [x | aggm]; aggm = hs @ W2m + deg*b2m
        if (lane < D_MSG) {
            float a = (float)deg[nn] * b2m[lane];
#pragma unroll 8
            for (int k = 0; k < D_H; ++k)
                a += hs[cq][k] * W2m[(size_t)k * D_MSG + lane];
            in2[cq][D_IN + lane] = a;
        } else {
            in2[cq][lane - D_MSG] = x[(size_t)nn * D_IN + (lane - D_MSG)];
        }
        // wave-internal LDS RAW: no block barrier needed (same wave writes/reads)
        float hval = b1u[lane];
#pragma unroll 8
        for (int k = 0; k < D_IN + D_MSG; ++k)
            hval += in2[cq][k] * W1u[(size_t)k * D_H + lane];
        rh[cq][lane] = hval > 0.0f ? hval : 0.0f;

        const int m = lane & 31;
        float o = b2u[m];
#pragma unroll 8
        for (int j = 0; j < D_H; ++j)
            o += rh[cq][j] * W2u[(size_t)j * D_UP + m];
        if (lane < D_UP)
            out[(size_t)nn * D_UP + m] = o;
    }
}

extern "C" void kernel_launch(void* const* d_in, const int* in_sizes, int n_in,
                              void* d_out, int out_size, void* d_ws, size_t ws_size,
                              hipStream_t stream) {
    const float* x    = (const float*)d_in[0];
    // d_in[1] = degrees — unused by the reference computation
    const float* ef   = (const float*)d_in[2];
    const float* W1m  = (const float*)d_in[3];
    const float* b1m  = (const float*)d_in[4];
    const float* W2m  = (const float*)d_in[5];
    const float* b2m  = (const float*)d_in[6];
    const float* W1u  = (const float*)d_in[7];
    const float* b1u  = (const float*)d_in[8];
    const float* W2u  = (const float*)d_in[9];
    const float* b2u  = (const float*)d_in[10];
    const int*   ei   = (const int*)d_in[11];

    const int n_nodes = in_sizes[0] / D_IN;      // 50000
    const int n_edges = in_sizes[11] / 2;        // 1600000

    float* out = (float*)d_out;

    const int NBn = (n_nodes + 255) / 256;       // 196 (<=256 req'd for scan)
    const int NBe = (n_edges + 255) / 256;       // 6250 edge blocks
    const int NBc = (n_edges + 63) / 64;         // 25000 ef-cvt blocks

    // Workspace layout:
    //   P1           : n_nodes * D_H  f    (12.8 MB)
    //   P2b          : n_nodes * D_H  u16  (6.4 MB)
    //   edges_sorted : n_edges        int2 (12.8 MB)
    //   deg/offs     : n_nodes        i
    //   bsum         : 256            i
    //   W1Ep         : 8*64  v2h (2 KB)
    //   rank         : n_edges i      (6.4 MB)
    //   efh          : n_edges * 8 v2h (25.6 MB)  -- only if ws permits
    float*          P1  = (float*)d_ws;
    unsigned short* P2b = (unsigned short*)(P1 + (size_t)n_nodes * D_H);
    int2* edges_sorted  = (int2*)(P2b + (size_t)n_nodes * D_H);
    int* deg    = (int*)(edges_sorted + n_edges);
    int* offs   = deg    + n_nodes;
    int* bsum   = offs   + n_nodes;
    v2h* W1Ep   = (v2h*)(bsum + 256);
    int* rank   = (int*)(W1Ep + 8 * D_H);
    size_t efh_off = (((char*)(rank + n_edges) - (char*)d_ws) + 15) & ~(size_t)15;
    v2h* efh    = (v2h*)((char*)d_ws + efh_off);
    size_t need = efh_off + (size_t)n_edges * 8 * sizeof(v2h);
    const bool use_efh = ws_size >= need;

    hipMemsetAsync(deg, 0, (size_t)n_nodes * sizeof(int), stream);

    {
        int grid = NBn + NBe + 1 + (use_efh ? NBc : 0);
        prep_kernel<<<grid, 256, 0, stream>>>(
            x, W1m, b1m, ef, ei, P1, P2b, deg, rank, W1Ep, efh,
            n_nodes, n_edges, NBn, NBe);
    }

    scan_reduce_kernel<<<NBn, 256, 0, stream>>>(deg, bsum, n_nodes);
    scan_final_kernel<<<NBn, 256, 0, stream>>>(deg, bsum, offs, n_nodes, NBn);

    scatter_kernel<<<NBe, 256, 0, stream>>>(ei, rank, offs, edges_sorted, n_edges);

    {
        int grid = (n_nodes + 3) / 4;   // 4 nodes/block, 4 waves = comp quarters
        if (use_efh)
            gather_kernel<1><<<grid, 256, 0, stream>>>(
                ef, efh, W1Ep, P1, P2b, deg, offs, edges_sorted,
                x, b2m, W2m, W1u, b1u, W2u, b2u, out, n_nodes);
        else
            gather_kernel<0><<<grid, 256, 0, stream>>>(
                ef, efh, W1Ep, P1, P2b, deg, offs, edges_sorted,
                x, b2m, W2m, W1u, b1u, W2u, b2u, out, n_nodes);
    }
}

// Round 10
// 450.750 us; speedup vs baseline: 2.6411x; 2.6411x over previous
//
#include <hip/hip_runtime.h>
#include <hip/hip_bf16.h>

#define D_IN  32
#define D_EF  16
#define D_H   64
#define D_MSG 32
#define D_UP  32

// NOTE: __builtin_amdgcn_cvt_pkrtz / fdot2 use the __fp16-based vector type;
// _Float16-based ext vectors are treated as incompatible by clang.
typedef __fp16 v2h __attribute__((ext_vector_type(2)));

// bf16 helpers: pack two fp32 -> uint32 (RNE), unpack low/high half
__device__ __forceinline__ unsigned bf16pair(float a, float b) {
    unsigned ua = __float_as_uint(a);
    ua = (ua + 0x7fffu + ((ua >> 16) & 1u)) >> 16;
    unsigned ub = __float_as_uint(b);
    ub = (ub + 0x7fffu + ((ub >> 16) & 1u)) >> 16;
    return ua | (ub << 16);
}
__device__ __forceinline__ float bf_lo(unsigned u) { return __uint_as_float(u << 16); }
__device__ __forceinline__ float bf_hi(unsigned u) { return __uint_as_float(u & 0xffff0000u); }
__device__ __forceinline__ v2h u2h(unsigned u) {
    union { unsigned u; v2h h; } c; c.u = u; return c.h;
}

// ---------------------------------------------------------------------------
// Fused front-end (independent stages dispatched by block range):
//   blocks [0, NBn)                  : node_pre (P1 fp32, P2 bf16)
//   blocks [NBn, NBn+NBe)            : hist + rank (atomicAdd returns rank)
//   block  NBn+NBe                   : W1E pair-packing for fdot2
//   blocks (NBn+NBe, NBn+NBe+NBc]    : ef -> fp16 prepack (only if efh fits;
//                                      streamed once, overlaps hist latency)
// ---------------------------------------------------------------------------
__global__ __launch_bounds__(256) void prep_kernel(
    const float* __restrict__ x,
    const float* __restrict__ W1m,
    const float* __restrict__ b1m,
    const float* __restrict__ ef,
    const int*   __restrict__ ei,
    float* __restrict__ P1,
    unsigned short* __restrict__ P2b,
    int* __restrict__ deg,
    int* __restrict__ rank,
    v2h* __restrict__ W1Ep,
    v2h* __restrict__ efh,
    int n_nodes, int n_edges, int NBn, int NBe)
{
    int b = blockIdx.x;

    if (b < NBn) {
        // ---------------- node_pre ----------------
        int i = b * 256 + threadIdx.x;
        if (i >= n_nodes) return;

        float xi[D_IN];
        const float4* xp = (const float4*)(x + (size_t)i * D_IN);
#pragma unroll
        for (int k4 = 0; k4 < D_IN / 4; ++k4) {
            float4 v = xp[k4];
            xi[4 * k4 + 0] = v.x; xi[4 * k4 + 1] = v.y;
            xi[4 * k4 + 2] = v.z; xi[4 * k4 + 3] = v.w;
        }
        {
            float acc[D_H];
#pragma unroll
            for (int j = 0; j < D_H; ++j) acc[j] = b1m[j];
            for (int k = 0; k < D_IN; ++k) {
                float xv = xi[k];
                const float* wr = W1m + (size_t)k * D_H;
#pragma unroll
                for (int j = 0; j < D_H; ++j) acc[j] += xv * wr[j];
            }
            float4* o = (float4*)(P1 + (size_t)i * D_H);
#pragma unroll
            for (int j4 = 0; j4 < D_H / 4; ++j4)
                o[j4] = make_float4(acc[4 * j4], acc[4 * j4 + 1],
                                    acc[4 * j4 + 2], acc[4 * j4 + 3]);
        }
        {
            float acc[D_H];
#pragma unroll
            for (int j = 0; j < D_H; ++j) acc[j] = 0.0f;
            for (int k = 0; k < D_IN; ++k) {
                float xv = xi[k];
                const float* wr = W1m + (size_t)(k + D_IN) * D_H;
#pragma unroll
                for (int j = 0; j < D_H; ++j) acc[j] += xv * wr[j];
            }
            uint4* o = (uint4*)(P2b + (size_t)i * D_H);
#pragma unroll
            for (int j8 = 0; j8 < D_H / 8; ++j8) {
                uint4 q;
                q.x = bf16pair(acc[8 * j8 + 0], acc[8 * j8 + 1]);
                q.y = bf16pair(acc[8 * j8 + 2], acc[8 * j8 + 3]);
                q.z = bf16pair(acc[8 * j8 + 4], acc[8 * j8 + 5]);
                q.w = bf16pair(acc[8 * j8 + 6], acc[8 * j8 + 7]);
                o[j8] = q;
            }
        }
    } else if (b < NBn + NBe) {
        // ---------------- hist + rank ----------------
        int e = (b - NBn) * 256 + threadIdx.x;
        if (e < n_edges)
            rank[e] = atomicAdd(&deg[ei[n_edges + e]], 1);
    } else if (b == NBn + NBe) {
        // ---------------- pack W1E for fdot2: [kp][c] ----------------
        int t = threadIdx.x;
        const float* W1E = W1m + (size_t)(2 * D_IN) * D_H;
        for (int idx = t; idx < 8 * D_H; idx += 256) {
            int kp = idx >> 6, c = idx & 63;
            W1Ep[idx] = __builtin_amdgcn_cvt_pkrtz(W1E[(2 * kp) * D_H + c],
                                                   W1E[(2 * kp + 1) * D_H + c]);
        }
    } else {
        // ---------------- ef -> fp16 prepack (64 rows/block) ----------------
        int cb  = b - (NBn + NBe + 1);
        int row = cb * 64 + (threadIdx.x >> 2);
        int q   = threadIdx.x & 3;
        if (row < n_edges) {
            const float4* fp = (const float4*)(ef + (size_t)row * D_EF + q * 4);
            float4 f = fp[0];
            v2h* o = efh + (size_t)row * 8 + q * 2;
            o[0] = __builtin_amdgcn_cvt_pkrtz(f.x, f.y);
            o[1] = __builtin_amdgcn_cvt_pkrtz(f.z, f.w);
        }
    }
}

// ---------------------------------------------------------------------------
// 2-phase scan: reduce -> final (each final block redundantly scans the
// <=256 block sums in LDS; no 1-block middle kernel bubble).
// ---------------------------------------------------------------------------
__global__ __launch_bounds__(256) void scan_reduce_kernel(
    const int* __restrict__ deg, int* __restrict__ bsum, int n_nodes)
{
    int idx = blockIdx.x * 256 + threadIdx.x;
    int v = (idx < n_nodes) ? deg[idx] : 0;
#pragma unroll
    for (int o = 1; o < 64; o <<= 1) v += __shfl_xor(v, o, 64);
    __shared__ int ws[4];
    int lane = threadIdx.x & 63, w = threadIdx.x >> 6;
    if (lane == 0) ws[w] = v;
    __syncthreads();
    if (threadIdx.x == 0) bsum[blockIdx.x] = ws[0] + ws[1] + ws[2] + ws[3];
}

__global__ __launch_bounds__(256) void scan_final_kernel(
    const int* __restrict__ deg, const int* __restrict__ bsum,
    int* __restrict__ offs, int n_nodes, int nb)
{
    __shared__ int sb[256];
    __shared__ int sdata[256];
    int t = threadIdx.x;

    sb[t] = (t < nb) ? bsum[t] : 0;
    __syncthreads();
    for (int off = 1; off < 256; off <<= 1) {
        int u = (t >= off) ? sb[t - off] : 0;
        __syncthreads();
        sb[t] += u;
        __syncthreads();
    }
    int base = (blockIdx.x > 0) ? sb[blockIdx.x - 1] : 0;

    int idx = blockIdx.x * 256 + t;
    sdata[t] = (idx < n_nodes) ? deg[idx] : 0;
    __syncthreads();
    for (int off = 1; off < 256; off <<= 1) {
        int u = (t >= off) ? sdata[t - off] : 0;
        __syncthreads();
        sdata[t] += u;
        __syncthreads();
    }
    if (idx < n_nodes) offs[idx] = base + ((t > 0) ? sdata[t - 1] : 0);
}

// ---------------------------------------------------------------------------
// Atomic-free scatter: pos = offs[dst] + rank[e] (unique by construction).
// REGULAR stores (round-3 lesson: L2 write-merge makes this cheap; nt stores
// caused 13x write amplification).
// ---------------------------------------------------------------------------
__global__ __launch_bounds__(256) void scatter_kernel(
    const int* __restrict__ ei,
    const int* __restrict__ rank,
    const int* __restrict__ offs,
    int2* __restrict__ edges_sorted,
    int n_edges)
{
    int e = blockIdx.x * blockDim.x + threadIdx.x;
    if (e < n_edges) {
        int s = ei[e];
        int d = ei[n_edges + e];
        int pos = offs[d] + rank[e];
        edges_sorted[pos] = make_int2(e, s);
    }
}

// ---------------------------------------------------------------------------
// Gather-aggregate — EXACT round-2 proven structure (131 us, VGPR 40,
// occupancy 58%): 4 nodes/block, comp-quarter per wave (hacc = 16 VGPRs,
// W1E slice SGPR-fed), 16 edge-slots -> 16 edges in flight per wave.
// Only delta: USE_EFH loads pre-converted fp16 ef rows (32B instead of 64B,
// deletes 8 cvt_pkrtz per edge-quarter). NO fused epilogue: rounds 8/9
// proved it either collapses occupancy (VGPR 100 -> 22%, 296 us) or, if
// capped, spills INSIDE the hot loop (3.7 GB scratch traffic, 925 us).
// ---------------------------------------------------------------------------
template<int USE_EFH>
__global__ __launch_bounds__(256, 6) void gather_kernel(
    const float* __restrict__ ef,
    const v2h*  __restrict__ efh,
    const v2h*  __restrict__ W1Ep,
    const float* __restrict__ P1,
    const unsigned short* __restrict__ P2b,
    const int*  __restrict__ deg,
    const int*  __restrict__ offs,
    const int2* __restrict__ edges_sorted,
    float* __restrict__ hagg,
    int n_nodes)
{
    const int lane = threadIdx.x & 63;
    const int cq   = __builtin_amdgcn_readfirstlane((int)(threadIdx.x >> 6));
    const int g    = lane >> 4;        // node sub-index in block
    const int t    = lane & 15;        // edge slot
    const int n    = blockIdx.x * 4 + g;
    if (n >= n_nodes) return;

    const int start = offs[n];
    const int end   = start + deg[n];

    float p1q[16];
    {
        const float4* pp = (const float4*)(P1 + (size_t)n * D_H + cq * 16);
#pragma unroll
        for (int q = 0; q < 4; ++q) {
            float4 v = pp[q];
            p1q[4 * q + 0] = v.x; p1q[4 * q + 1] = v.y;
            p1q[4 * q + 2] = v.z; p1q[4 * q + 3] = v.w;
        }
    }

    const v2h* wbase = W1Ep + 16 * cq;   // wave-uniform -> scalar loads

    float hacc[16];
#pragma unroll
    for (int c = 0; c < 16; ++c) hacc[c] = 0.0f;

    for (int i = start + t; i < end; i += 16) {
        int2 es = edges_sorted[i];

        v2h efr[8];
        if (USE_EFH) {
            const uint4* ep = (const uint4*)(efh + (size_t)(unsigned)es.x * 8);
            uint4 u0 = ep[0], u1 = ep[1];
            efr[0] = u2h(u0.x); efr[1] = u2h(u0.y);
            efr[2] = u2h(u0.z); efr[3] = u2h(u0.w);
            efr[4] = u2h(u1.x); efr[5] = u2h(u1.y);
            efr[6] = u2h(u1.z); efr[7] = u2h(u1.w);
        } else {
            const float4* efp = (const float4*)(ef + (size_t)(unsigned)es.x * D_EF);
            float4 f0 = efp[0], f1 = efp[1], f2 = efp[2], f3 = efp[3];
            efr[0] = __builtin_amdgcn_cvt_pkrtz(f0.x, f0.y);
            efr[1] = __builtin_amdgcn_cvt_pkrtz(f0.z, f0.w);
            efr[2] = __builtin_amdgcn_cvt_pkrtz(f1.x, f1.y);
            efr[3] = __builtin_amdgcn_cvt_pkrtz(f1.z, f1.w);
            efr[4] = __builtin_amdgcn_cvt_pkrtz(f2.x, f2.y);
            efr[5] = __builtin_amdgcn_cvt_pkrtz(f2.z, f2.w);
            efr[6] = __builtin_amdgcn_cvt_pkrtz(f3.x, f3.y);
            efr[7] = __builtin_amdgcn_cvt_pkrtz(f3.z, f3.w);
        }

        const uint4* p2u = (const uint4*)(P2b + (size_t)(unsigned)es.y * D_H + cq * 16);
        uint4 b0 = p2u[0], b1 = p2u[1];

#pragma unroll
        for (int jj = 0; jj < 2; ++jj) {
            uint4 bb = jj ? b1 : b0;
            float h[8];
            h[0] = p1q[8 * jj + 0] + bf_lo(bb.x);
            h[1] = p1q[8 * jj + 1] + bf_hi(bb.x);
            h[2] = p1q[8 * jj + 2] + bf_lo(bb.y);
            h[3] = p1q[8 * jj + 3] + bf_hi(bb.y);
            h[4] = p1q[8 * jj + 4] + bf_lo(bb.z);
            h[5] = p1q[8 * jj + 5] + bf_hi(bb.z);
            h[6] = p1q[8 * jj + 6] + bf_lo(bb.w);
            h[7] = p1q[8 * jj + 7] + bf_hi(bb.w);
#pragma unroll
            for (int kp = 0; kp < D_EF / 2; ++kp) {
                const v2h* wr = wbase + kp * D_H + 8 * jj;
#pragma unroll
                for (int c8 = 0; c8 < 8; ++c8)
                    h[c8] = __builtin_amdgcn_fdot2(efr[kp], wr[c8], h[c8], false);
            }
#pragma unroll
            for (int c8 = 0; c8 < 8; ++c8) {
                float r = h[c8] > 0.0f ? h[c8] : 0.0f;
                hacc[8 * jj + c8] += r;
            }
        }
    }

    // ---- 4-stage butterfly compaction across the node's 16 lanes ----
    float r1[8];
    {
        const bool up = (t & 8) != 0;
#pragma unroll
        for (int c = 0; c < 8; ++c) {
            float lo = hacc[c]     + __shfl_xor(hacc[c],     8, 16);
            float hi = hacc[c + 8] + __shfl_xor(hacc[c + 8], 8, 16);
            r1[c] = up ? hi : lo;
        }
    }
    float r2[4];
    {
        const bool up = (t & 4) != 0;
#pragma unroll
        for (int c = 0; c < 4; ++c) {
            float lo = r1[c]     + __shfl_xor(r1[c],     4, 16);
            float hi = r1[c + 4] + __shfl_xor(r1[c + 4], 4, 16);
            r2[c] = up ? hi : lo;
        }
    }
    float r3[2];
    {
        const bool up = (t & 2) != 0;
#pragma unroll
        for (int c = 0; c < 2; ++c) {
            float lo = r2[c]     + __shfl_xor(r2[c],     2, 16);
            float hi = r2[c + 2] + __shfl_xor(r2[c + 2], 2, 16);
            r3[c] = up ? hi : lo;
        }
    }
    float r4;
    {
        const bool up = (t & 1) != 0;
        float lo = r3[0] + __shfl_xor(r3[0], 1, 16);
        float hi = r3[1] + __shfl_xor(r3[1], 1, 16);
        r4 = up ? hi : lo;
    }

    // lane t holds comp t of this wave's quarter -> coalesced 64B per group
    hagg[(size_t)n * D_H + cq * 16 + t] = r4;
}

// ---------------------------------------------------------------------------
// Per-node update MLP. Absorbs the hoisted layer-2:
//   aggm = hsum @ W2m + deg*b2m
//   out  = relu([x, aggm] @ W1u + b1u) @ W2u + b2u
// ---------------------------------------------------------------------------
__global__ __launch_bounds__(256) void node_upd_kernel(
    const float* __restrict__ x,
    const float* __restrict__ hagg,
    const int*   __restrict__ deg,
    const float* __restrict__ b2m,
    const float* __restrict__ W2m,
    const float* __restrict__ W1u,
    const float* __restrict__ b1u,
    const float* __restrict__ W2u,
    const float* __restrict__ b2u,
    float* __restrict__ out,
    int n_nodes)
{
    int i = blockIdx.x * blockDim.x + threadIdx.x;
    if (i >= n_nodes) return;

    float in[D_IN + D_MSG];
    const float4* xp = (const float4*)(x + (size_t)i * D_IN);
#pragma unroll
    for (int k4 = 0; k4 < D_IN / 4; ++k4) {
        float4 v = xp[k4];
        in[4 * k4 + 0] = v.x; in[4 * k4 + 1] = v.y;
        in[4 * k4 + 2] = v.z; in[4 * k4 + 3] = v.w;
    }

    float dc = (float)deg[i];
#pragma unroll
    for (int m = 0; m < D_MSG; ++m) in[D_IN + m] = dc * b2m[m];

    const float4* hp = (const float4*)(hagg + (size_t)i * D_H);
    for (int j4 = 0; j4 < D_H / 4; ++j4) {
        float4 v = hp[j4];
        const float* w0 = W2m + (size_t)(4 * j4 + 0) * D_MSG;
        const float* w1 = W2m + (size_t)(4 * j4 + 1) * D_MSG;
        const float* w2 = W2m + (size_t)(4 * j4 + 2) * D_MSG;
        const float* w3 = W2m + (size_t)(4 * j4 + 3) * D_MSG;
#pragma unroll
        for (int m = 0; m < D_MSG; ++m)
            in[D_IN + m] += v.x * w0[m] + v.y * w1[m] + v.z * w2[m] + v.w * w3[m];
    }

    float h[D_H];
#pragma unroll
    for (int j = 0; j < D_H; ++j) h[j] = b1u[j];
    for (int k = 0; k < D_IN + D_MSG; ++k) {
        float v = in[k];
        const float* wr = W1u + (size_t)k * D_H;
#pragma unroll
        for (int j = 0; j < D_H; ++j) h[j] += v * wr[j];
    }

    float o[D_UP];
#pragma unroll
    for (int m = 0; m < D_UP; ++m) o[m] = b2u[m];
    for (int j = 0; j < D_H; ++j) {
        float r = h[j] > 0.0f ? h[j] : 0.0f;
        const float* wr = W2u + (size_t)j * D_UP;
#pragma unroll
        for (int m = 0; m < D_UP; ++m) o[m] += r * wr[m];
    }

    float4* op = (float4*)(out + (size_t)i * D_UP);
#pragma unroll
    for (int m4 = 0; m4 < D_UP / 4; ++m4)
        op[m4] = make_float4(o[4 * m4], o[4 * m4 + 1], o[4 * m4 + 2], o[4 * m4 + 3]);
}

extern "C" void kernel_launch(void* const* d_in, const int* in_sizes, int n_in,
                              void* d_out, int out_size, void* d_ws, size_t ws_size,
                              hipStream_t stream) {
    const float* x    = (const float*)d_in[0];
    // d_in[1] = degrees — unused by the reference computation
    const float* ef   = (const float*)d_in[2];
    const float* W1m  = (const float*)d_in[3];
    const float* b1m  = (const float*)d_in[4];
    const float* W2m  = (const float*)d_in[5];
    const float* b2m  = (const float*)d_in[6];
    const float* W1u  = (const float*)d_in[7];
    const float* b1u  = (const float*)d_in[8];
    const float* W2u  = (const float*)d_in[9];
    const float* b2u  = (const float*)d_in[10];
    const int*   ei   = (const int*)d_in[11];

    const int n_nodes = in_sizes[0] / D_IN;      // 50000
    const int n_edges = in_sizes[11] / 2;        // 1600000

    float* out = (float*)d_out;

    const int NBn = (n_nodes + 255) / 256;       // 196 (<=256 req'd for scan)
    const int NBe = (n_edges + 255) / 256;       // 6250 edge blocks
    const int NBc = (n_edges + 63) / 64;         // 25000 ef-cvt blocks

    // Workspace layout:
    //   P1           : n_nodes * D_H  f    (12.8 MB)
    //   P2b          : n_nodes * D_H  u16  (6.4 MB)
    //   edges_sorted : n_edges        int2 (12.8 MB)
    //   deg/offs     : n_nodes        i
    //   bsum         : 256            i
    //   W1Ep         : 8*64  v2h (2 KB)
    //   rank         : n_edges i      (6.4 MB, live prep -> scatter)
    //   efh          : n_edges*8 v2h  (25.6 MB, live prep -> gather) [if fits]
    //   hagg         : n_nodes*D_H f  (12.8 MB, live gather -> node_upd)
    //     - efh path: hagg placed AFTER efh (both live during gather)
    //     - fallback: hagg aliases rank (round-2 exact layout)
    float*          P1  = (float*)d_ws;
    unsigned short* P2b = (unsigned short*)(P1 + (size_t)n_nodes * D_H);
    int2* edges_sorted  = (int2*)(P2b + (size_t)n_nodes * D_H);
    int* deg    = (int*)(edges_sorted + n_edges);
    int* offs   = deg    + n_nodes;
    int* bsum   = offs   + n_nodes;
    v2h* W1Ep   = (v2h*)(bsum + 256);
    int* rank   = (int*)(W1Ep + 8 * D_H);
    size_t efh_off = (((char*)(rank + n_edges) - (char*)d_ws) + 15) & ~(size_t)15;
    v2h* efh    = (v2h*)((char*)d_ws + efh_off);
    size_t hagg_off = efh_off + (size_t)n_edges * 8 * sizeof(v2h);
    size_t need = hagg_off + (size_t)n_nodes * D_H * sizeof(float);
    const bool use_efh = ws_size >= need;
    float* hagg = use_efh ? (float*)((char*)d_ws + hagg_off)
                          : (float*)rank;        // round-2 alias fallback

    hipMemsetAsync(deg, 0, (size_t)n_nodes * sizeof(int), stream);

    {
        int grid = NBn + NBe + 1 + (use_efh ? NBc : 0);
        prep_kernel<<<grid, 256, 0, stream>>>(
            x, W1m, b1m, ef, ei, P1, P2b, deg, rank, W1Ep, efh,
            n_nodes, n_edges, NBn, NBe);
    }

    scan_reduce_kernel<<<NBn, 256, 0, stream>>>(deg, bsum, n_nodes);
    scan_final_kernel<<<NBn, 256, 0, stream>>>(deg, bsum, offs, n_nodes, NBn);

    scatter_kernel<<<NBe, 256, 0, stream>>>(ei, rank, offs, edges_sorted, n_edges);

    {
        int grid = (n_nodes + 3) / 4;   // 4 nodes/block, 4 waves = comp quarters
        if (use_efh)
            gather_kernel<1><<<grid, 256, 0, stream>>>(
                ef, efh, W1Ep, P1, P2b, deg, offs, edges_sorted, hagg, n_nodes);
        else
            gather_kernel<0><<<grid, 256, 0, stream>>>(
                ef, efh, W1Ep, P1, P2b, deg, offs, edges_sorted, hagg, n_nodes);
    }
    node_upd_kernel<<<NBn, 256, 0, stream>>>(x, hagg, deg, b2m, W2m,
                                             W1u, b1u, W2u, b2u, out, n_nodes);
}